// Round 5
// baseline (581.254 us; speedup 1.0000x reference)
//
#include <hip/hip_runtime.h>

// Problem constants (fixed by reference): B=4, C=64, H=W=64 -> N=4096
#define NN 4096
#define CD 64

typedef __attribute__((ext_vector_type(8))) short bf16x8; // 8 bf16 in 4 VGPRs
typedef __attribute__((ext_vector_type(4))) float f32x4;

// Device-global workspace, fully rewritten each launch.
__device__ unsigned short g_Qh[2][4][NN][CD]; // Q^T hi  [n][c], c contiguous
__device__ unsigned short g_Ql[2][4][NN][CD]; // Q^T lo
__device__ unsigned short g_Kh[2][4][NN][CD]; // K^T hi
__device__ unsigned short g_Kl[2][4][NN][CD]; // K^T lo
__device__ float          g_Vf[2][4][CD][NN]; // V fp32 (pre-fold)
__device__ unsigned short g_Vb[2][4][CD][NN]; // V*g/Z bf16 (RNE)
__device__ float          g_O [2][4][CD][NN]; // per-branch attn out (fp32)
__device__ float          g_Zp[4][2][4][NN];  // partial softmax denoms (j-split)

__device__ inline f32x4 mfma16(bf16x8 a, bf16x8 b, f32x4 c) {
  return __builtin_amdgcn_mfma_f32_16x16x32_bf16(a, b, c, 0, 0, 0);
}

// Truncation hi + RNE lo split: x ~= hi + lo, |x-(hi+lo)| <= 2^-17 |x|
__device__ inline void split_bf(float x, unsigned short& h, unsigned short& l) {
  unsigned u = __builtin_bit_cast(unsigned, x);
  h = (unsigned short)(u >> 16);
  float hf = __builtin_bit_cast(float, u & 0xffff0000u);
  unsigned v = __builtin_bit_cast(unsigned, x - hf);
  v += 0x7fffu + ((v >> 16) & 1u);
  l = (unsigned short)(v >> 16);
}

// Pack two f32 -> u32 holding 2 RNE-rounded bf16.
__device__ inline unsigned rne2(float a, float b) {
  unsigned ua = __builtin_bit_cast(unsigned, a);
  unsigned ub = __builtin_bit_cast(unsigned, b);
  ua += 0x7fffu + ((ua >> 16) & 1u);
  ub += 0x7fffu + ((ub >> 16) & 1u);
  return (ua >> 16) | (ub & 0xffff0000u);
}

struct ProjArgs {
  const float* x;
  const float* W[6];
  const float* bias[6];
};

// ---------------------------------------------------------------------------
// Kernel 1: six 1x1-conv projections, fp32 compute.
// Q/K written transposed ([n][c], c contiguous) split into bf16 hi/lo.
// V written fp32 [c][n] (bf16 RNE happens after the 1/Z fold).
// ---------------------------------------------------------------------------
__global__ __launch_bounds__(256) void proj_kernel(ProjArgs a) {
  __shared__ float Wt[64][68];
  __shared__ float bs[64];
  const int tid = threadIdx.x;
  const int m = blockIdx.z; // 0..5 = qh,kh,vh,ql,kl,vl
  const float* __restrict__ W = a.W[m];
#pragma unroll
  for (int k = 0; k < 16; ++k) {
    int t = k * 256 + tid; // t = o*64 + c
    Wt[t & 63][t >> 6] = W[t];
  }
  if (tid < 64) bs[tid] = a.bias[m][tid];
  __syncthreads();

  const int b = blockIdx.y;
  const int n = (blockIdx.x << 6) + (tid & 63);
  const int og = tid >> 6;
  const float* __restrict__ xp = a.x + ((size_t)b * CD) * NN + n;

  float acc[16];
#pragma unroll
  for (int k = 0; k < 16; ++k) acc[k] = bs[og * 16 + k];

#pragma unroll 4
  for (int c = 0; c < 64; ++c) {
    float xv = xp[(size_t)c * NN];
    float w[16];
    *(float4*)&w[0]  = *(const float4*)&Wt[c][og * 16 + 0];
    *(float4*)&w[4]  = *(const float4*)&Wt[c][og * 16 + 4];
    *(float4*)&w[8]  = *(const float4*)&Wt[c][og * 16 + 8];
    *(float4*)&w[12] = *(const float4*)&Wt[c][og * 16 + 12];
#pragma unroll
    for (int k = 0; k < 16; ++k) acc[k] += w[k] * xv;
  }

  const int br = m / 3, kind = m % 3;
  if (kind == 2) { // V: fp32 [c][n]
    float* dst = &g_Vf[br][b][0][0] + n;
#pragma unroll
    for (int k = 0; k < 16; ++k) dst[(size_t)(og * 16 + k) * NN] = acc[k];
  } else { // Q/K: bf16 hi/lo, transposed [n][c]
    unsigned short hi[16], lo[16];
#pragma unroll
    for (int k = 0; k < 16; ++k) split_bf(acc[k], hi[k], lo[k]);
    unsigned short* dh = (kind == 0) ? &g_Qh[br][b][n][og * 16] : &g_Kh[br][b][n][og * 16];
    unsigned short* dl = (kind == 0) ? &g_Ql[br][b][n][og * 16] : &g_Kl[br][b][n][og * 16];
    *(uint4*)dh       = *(const uint4*)&hi[0];
    *(uint4*)(dh + 8) = *(const uint4*)&hi[8];
    *(uint4*)dl       = *(const uint4*)&lo[0];
    *(uint4*)(dl + 8) = *(const uint4*)&lo[8];
  }
}

// ---------------------------------------------------------------------------
// Kernel 2: pass 1 — Zp[js][i] = sum_{j in js-range} exp(S[i,j]).
// grid 2048 (bid&7=image -> XCD pin, (bid>>3)&3 = j-split, bid>>5 = i-block).
// K^T fragments double-buffered in REGISTERS: next tile's loads issue before
// this tile's MFMAs, hiding L2 latency under MFMA+exp. No LDS in loop.
// ---------------------------------------------------------------------------
__global__ __launch_bounds__(256) void pass1_kernel() {
  __shared__ float zbuf[2][64];

  const int tid = threadIdx.x;
  const int bid = blockIdx.x;
  const int img = bid & 7;
  const int br = img >> 2, b = img & 3;
  const int js = (bid >> 3) & 3;
  const int i0 = (bid >> 5) << 6;

  const int lane = tid & 63, w = tid >> 6;
  const int wi = w >> 1, wj = w & 1;
  const int lm = lane & 15, q = lane >> 4;

  const unsigned short* __restrict__ QhB = &g_Qh[br][b][0][0];
  const unsigned short* __restrict__ QlB = &g_Ql[br][b][0][0];
  const unsigned short* __restrict__ KhB = &g_Kh[br][b][0][0];
  const unsigned short* __restrict__ KlB = &g_Kl[br][b][0][0];

  // Static A-frags (Q): [it][cstep][hi/lo]
  bf16x8 qa[2][2][2];
#pragma unroll
  for (int it = 0; it < 2; ++it)
#pragma unroll
    for (int cs = 0; cs < 2; ++cs) {
      size_t off = (size_t)(i0 + wi * 32 + it * 16 + lm) * 64 + cs * 32 + q * 8;
      qa[it][cs][0] = *(const bf16x8*)(QhB + off);
      qa[it][cs][1] = *(const bf16x8*)(QlB + off);
    }

  float zacc[2][4];
#pragma unroll
  for (int it = 0; it < 2; ++it)
#pragma unroll
    for (int r = 0; r < 4; ++r) zacc[it][r] = 0.f;

  const int jwave = wj * 32 + lm;

  auto loadk = [&](bf16x8 (&dst)[2][2][2], int tt) {
    const int jb = ((js << 4) + tt) << 6;
#pragma unroll
    for (int jt = 0; jt < 2; ++jt) {
      size_t rowo = (size_t)(jb + jwave + jt * 16) * 64 + q * 8;
#pragma unroll
      for (int cs = 0; cs < 2; ++cs) {
        dst[jt][cs][0] = *(const bf16x8*)(KhB + rowo + cs * 32);
        dst[jt][cs][1] = *(const bf16x8*)(KlB + rowo + cs * 32);
      }
    }
  };

  auto scomp = [&](bf16x8 (&kb)[2][2][2]) {
    const f32x4 zf = {0.f, 0.f, 0.f, 0.f};
    f32x4 s[2][2];
    __builtin_amdgcn_s_setprio(1);
#pragma unroll
    for (int it = 0; it < 2; ++it)
#pragma unroll
      for (int jt = 0; jt < 2; ++jt) {
        f32x4 t = mfma16(qa[it][0][0], kb[jt][0][0], zf);
        t = mfma16(qa[it][1][0], kb[jt][1][0], t);
        t = mfma16(qa[it][0][0], kb[jt][0][1], t);
        t = mfma16(qa[it][1][0], kb[jt][1][1], t);
        t = mfma16(qa[it][0][1], kb[jt][0][0], t);
        t = mfma16(qa[it][1][1], kb[jt][1][0], t);
        s[it][jt] = t;
      }
    __builtin_amdgcn_s_setprio(0);
#pragma unroll
    for (int it = 0; it < 2; ++it)
#pragma unroll
      for (int jt = 0; jt < 2; ++jt) {
        zacc[it][0] += __expf(s[it][jt][0]);
        zacc[it][1] += __expf(s[it][jt][1]);
        zacc[it][2] += __expf(s[it][jt][2]);
        zacc[it][3] += __expf(s[it][jt][3]);
      }
  };

  bf16x8 kA[2][2][2], kB[2][2][2];
  loadk(kA, 0);
  for (int t2 = 0; t2 < 8; ++t2) {
    const int to = t2 * 2 + 1;
    loadk(kB, to);      // issue odd tile's loads; land under even compute
    scomp(kA);
    if (to < 15) loadk(kA, to + 1); // issue next even tile's loads
    scomp(kB);
  }

#pragma unroll
  for (int mm = 1; mm < 16; mm <<= 1)
#pragma unroll
    for (int it = 0; it < 2; ++it)
#pragma unroll
      for (int r = 0; r < 4; ++r) zacc[it][r] += __shfl_xor(zacc[it][r], mm, 64);

  if (lm == 0) {
#pragma unroll
    for (int it = 0; it < 2; ++it)
#pragma unroll
      for (int r = 0; r < 4; ++r)
        zbuf[wj][wi * 32 + it * 16 + q * 4 + r] = zacc[it][r];
  }
  __syncthreads();
  if (tid < 64) g_Zp[js][br][b][i0 + tid] = zbuf[0][tid] + zbuf[1][tid];
}

// ---------------------------------------------------------------------------
// Kernel 3: Z = sum of 4 partials; fold g/Z into V; RNE-round to bf16.
// ---------------------------------------------------------------------------
__global__ __launch_bounds__(256) void scalev_kernel(const float* __restrict__ g1,
                                                     const float* __restrict__ g2) {
  int idx = blockIdx.x * 256 + threadIdx.x; // 2*4*64*1024 float4 chunks
  int i4 = idx & 1023;
  int c  = (idx >> 10) & 63;
  int b  = (idx >> 16) & 3;
  int br = idx >> 18;
  float g = br ? g2[0] : g1[0];
  float4 z0 = *(const float4*)&g_Zp[0][br][b][i4 * 4];
  float4 z1 = *(const float4*)&g_Zp[1][br][b][i4 * 4];
  float4 z2 = *(const float4*)&g_Zp[2][br][b][i4 * 4];
  float4 z3 = *(const float4*)&g_Zp[3][br][b][i4 * 4];
  float4 z = {z0.x + z1.x + z2.x + z3.x, z0.y + z1.y + z2.y + z3.y,
              z0.z + z1.z + z2.z + z3.z, z0.w + z1.w + z2.w + z3.w};
  float4 v = *(const float4*)&g_Vf[br][b][c][i4 * 4];
  uint2 uh;
  uh.x = rne2(v.x * g / z.x, v.y * g / z.y);
  uh.y = rne2(v.z * g / z.z, v.w * g / z.w);
  *(uint2*)&g_Vb[br][b][c][i4 * 4] = uh;
}

// ---------------------------------------------------------------------------
// Kernel 4: pass 2 — O[c,j] = sum_i Vb[c,i] * P[i,j], P = exp(S)/Z (folded).
// grid 512 (bid&7 = image -> XCD pin, bid>>3 = 64-col j-block).
// NEW: each of the 4 waves owns 16 j-columns and computes S AND PV for them.
// The P exchange is wave-local (disjoint LDS rows) -> ZERO barriers in loop.
// S in bf16 hi/lo (3 MFMA terms); PV in single bf16 (RNE) — 32 MFMA/tile.
// Q issued right after its S-phase (dead regs), V right after PV: ~400-500
// cycles of compute cover L2 latency. setprio(1) wraps both MFMA clusters.
// ---------------------------------------------------------------------------
__global__ __launch_bounds__(256, 2) void pass2_kernel() {
  __shared__ unsigned short pt[64 * 64]; // [j-row][i] swizzled, bf16 P, 8 KiB

  const int tid = threadIdx.x;
  const int bid = blockIdx.x;
  const int img = bid & 7;
  const int br = img >> 2, b = img & 3;
  const int j0 = (bid >> 3) << 6;

  const int lane = tid & 63, w = tid >> 6;
  const int lm = lane & 15, q = lane >> 4;
  const int row = w * 16 + lm;  // LDS P row; per-wave rows are disjoint
  const int jcol = j0 + row;    // global j column owned by this lane
  const int sw = (row & 7) << 4;

  const unsigned short* __restrict__ QhB = &g_Qh[br][b][0][0];
  const unsigned short* __restrict__ QlB = &g_Ql[br][b][0][0];
  const unsigned short* __restrict__ KhB = &g_Kh[br][b][0][0];
  const unsigned short* __restrict__ KlB = &g_Kl[br][b][0][0];
  const unsigned short* __restrict__ VbB = &g_Vb[br][b][0][0];

  // Static B-frags (K^T rows = this lane's j-columns): [cstep][hi/lo]
  bf16x8 kb[2][2];
#pragma unroll
  for (int cs = 0; cs < 2; ++cs) {
    size_t off = (size_t)jcol * 64 + cs * 32 + q * 8;
    kb[cs][0] = *(const bf16x8*)(KhB + off);
    kb[cs][1] = *(const bf16x8*)(KlB + off);
  }

  bf16x8 qa[4][2][2]; // [it][cstep][hi/lo] — full 64-i tile
  bf16x8 va[4][2];    // [ct][kstep] — single bf16 V
  auto loadQ = [&](int ib) {
#pragma unroll
    for (int it = 0; it < 4; ++it)
#pragma unroll
      for (int cs = 0; cs < 2; ++cs) {
        size_t off = (size_t)(ib + it * 16 + lm) * 64 + cs * 32 + q * 8;
        qa[it][cs][0] = *(const bf16x8*)(QhB + off);
        qa[it][cs][1] = *(const bf16x8*)(QlB + off);
      }
  };
  auto loadV = [&](int ib) {
#pragma unroll
    for (int ct = 0; ct < 4; ++ct)
#pragma unroll
      for (int ks = 0; ks < 2; ++ks)
        va[ct][ks] = *(const bf16x8*)(VbB + (size_t)(ct * 16 + lm) * NN + ib + ks * 32 + q * 8);
  };
  loadQ(0);
  loadV(0);

  f32x4 oacc[4];
#pragma unroll
  for (int ct = 0; ct < 4; ++ct) oacc[ct] = (f32x4){0.f, 0.f, 0.f, 0.f};

  for (int tt = 0; tt < 64; ++tt) {
    const int inext = (tt + 1) << 6;
    // ---- S phase: S[i 64][j=jcol], hi/lo 3-term ----
    const f32x4 zf = {0.f, 0.f, 0.f, 0.f};
    f32x4 sacc[4];
    __builtin_amdgcn_s_setprio(1);
#pragma unroll
    for (int it = 0; it < 4; ++it) {
      f32x4 s = mfma16(qa[it][0][0], kb[0][0], zf);
      s = mfma16(qa[it][1][0], kb[1][0], s);
      s = mfma16(qa[it][0][0], kb[0][1], s);
      s = mfma16(qa[it][1][0], kb[1][1], s);
      s = mfma16(qa[it][0][1], kb[0][0], s);
      s = mfma16(qa[it][1][1], kb[1][0], s);
      sacc[it] = s;
    }
    __builtin_amdgcn_s_setprio(0);
    if (tt < 63) loadQ(inext); // qa dead after S; lands under exp+LDS+PV

    // ---- exp -> bf16 RNE -> per-wave LDS rows (no barrier) ----
#pragma unroll
    for (int it = 0; it < 4; ++it) {
      uint2 wpk;
      wpk.x = rne2(__expf(sacc[it][0]), __expf(sacc[it][1]));
      wpk.y = rne2(__expf(sacc[it][2]), __expf(sacc[it][3]));
      *(uint2*)((char*)pt + row * 128 + ((it * 32 + q * 8) ^ sw)) = wpk;
    }
    asm volatile("s_waitcnt lgkmcnt(0)" ::: "memory");
    __builtin_amdgcn_sched_barrier(0); // keep MFMAs from hoisting above wait

    // ---- PV phase: O[c][jcol] += V[c][i] * P[i][jcol] ----
    bf16x8 pb[2];
#pragma unroll
    for (int ks = 0; ks < 2; ++ks)
      pb[ks] = *(const bf16x8*)((const char*)pt + row * 128 + ((ks * 64 + q * 16) ^ sw));
    __builtin_amdgcn_s_setprio(1);
#pragma unroll
    for (int ct = 0; ct < 4; ++ct) {
      f32x4 o = mfma16(va[ct][0], pb[0], oacc[ct]);
      oacc[ct] = mfma16(va[ct][1], pb[1], o);
    }
    __builtin_amdgcn_s_setprio(0);
    if (tt < 63) loadV(inext); // va dead after PV; lands under next S+exp
  }

  float* __restrict__ Ob = &g_O[br][b][0][0];
#pragma unroll
  for (int ct = 0; ct < 4; ++ct)
#pragma unroll
    for (int r = 0; r < 4; ++r)
      Ob[(size_t)(ct * 16 + q * 4 + r) * NN + jcol] = oacc[ct][r];
}

// ---------------------------------------------------------------------------
// Kernel 5: final 1x1 conv over concat (g1/g2 already folded into V).
// ---------------------------------------------------------------------------
__global__ __launch_bounds__(256) void final_kernel(const float* __restrict__ Wf,
                                                    const float* __restrict__ bf,
                                                    float* __restrict__ out) {
  __shared__ float Wt[128][68];
  __shared__ float bs[64];
  const int tid = threadIdx.x;
#pragma unroll
  for (int k = 0; k < 32; ++k) {
    int t = k * 256 + tid; // t = o*128 + c'
    Wt[t & 127][t >> 7] = Wf[t];
  }
  if (tid < 64) bs[tid] = bf[tid];
  __syncthreads();

  const int b = blockIdx.y;
  const int n = (blockIdx.x << 6) + (tid & 63);
  const int og = tid >> 6;

  float acc[16];
#pragma unroll
  for (int k = 0; k < 16; ++k) acc[k] = bs[og * 16 + k];

#pragma unroll
  for (int br = 0; br < 2; ++br) {
    const float* __restrict__ Ob = &g_O[br][b][0][0];
#pragma unroll 4
    for (int c = 0; c < 64; ++c) {
      float xv = Ob[(size_t)c * NN + n];
      float wv[16];
      *(float4*)&wv[0]  = *(const float4*)&Wt[br * 64 + c][og * 16 + 0];
      *(float4*)&wv[4]  = *(const float4*)&Wt[br * 64 + c][og * 16 + 4];
      *(float4*)&wv[8]  = *(const float4*)&Wt[br * 64 + c][og * 16 + 8];
      *(float4*)&wv[12] = *(const float4*)&Wt[br * 64 + c][og * 16 + 12];
#pragma unroll
      for (int k = 0; k < 16; ++k) acc[k] += wv[k] * xv;
    }
  }

  float* op = out + ((size_t)b * CD) * NN + n;
#pragma unroll
  for (int k = 0; k < 16; ++k) op[(size_t)(og * 16 + k) * NN] = acc[k];
}

// ---------------------------------------------------------------------------
extern "C" void kernel_launch(void* const* d_in, const int* in_sizes, int n_in,
                              void* d_out, int out_size, void* d_ws, size_t ws_size,
                              hipStream_t stream) {
  (void)in_sizes; (void)n_in; (void)d_ws; (void)ws_size; (void)out_size;

  ProjArgs pa;
  pa.x = (const float*)d_in[0];
  for (int m = 0; m < 6; ++m) {
    pa.W[m]    = (const float*)d_in[1 + 2 * m];
    pa.bias[m] = (const float*)d_in[2 + 2 * m];
  }
  const float* g1 = (const float*)d_in[13];
  const float* g2 = (const float*)d_in[14];
  const float* Wf = (const float*)d_in[15];
  const float* bf = (const float*)d_in[16];
  float* out = (float*)d_out;

  proj_kernel<<<dim3(64, 4, 6), 256, 0, stream>>>(pa);
  pass1_kernel<<<dim3(2048), 256, 0, stream>>>();
  scalev_kernel<<<dim3(2048), 256, 0, stream>>>(g1, g2);
  pass2_kernel<<<dim3(512), 256, 0, stream>>>();
  final_kernel<<<dim3(64, 4), 256, 0, stream>>>(Wf, bf, out);
}

// Round 9
// 477.474 us; speedup vs baseline: 1.2174x; 1.2174x over previous
//
#include <hip/hip_runtime.h>

// Problem constants (fixed by reference): B=4, C=64, H=W=64 -> N=4096
#define NN 4096
#define CD 64

typedef __attribute__((ext_vector_type(8))) short bf16x8; // 8 bf16 in 4 VGPRs
typedef __attribute__((ext_vector_type(4))) float f32x4;

// Device-global workspace, fully rewritten each launch.
__device__ unsigned short g_Qh[2][4][NN][CD]; // Q^T hi  [n][c], c contiguous
__device__ unsigned short g_Ql[2][4][NN][CD]; // Q^T lo
__device__ unsigned short g_Kh[2][4][NN][CD]; // K^T hi
__device__ unsigned short g_Kl[2][4][NN][CD]; // K^T lo
__device__ float          g_Vf[2][4][CD][NN]; // V fp32 (pre-fold)
__device__ unsigned short g_Vb[2][4][CD][NN]; // V*g/Z bf16 (RNE)
__device__ float          g_O [2][4][CD][NN]; // per-branch attn out (fp32)
__device__ float          g_Zp[2][2][4][NN];  // partial softmax denoms (j-split)

__device__ inline f32x4 mfma16(bf16x8 a, bf16x8 b, f32x4 c) {
  return __builtin_amdgcn_mfma_f32_16x16x32_bf16(a, b, c, 0, 0, 0);
}

// Truncation hi + RNE lo split: x ~= hi + lo, |x-(hi+lo)| <= 2^-17 |x|
__device__ inline void split_bf(float x, unsigned short& h, unsigned short& l) {
  unsigned u = __builtin_bit_cast(unsigned, x);
  h = (unsigned short)(u >> 16);
  float hf = __builtin_bit_cast(float, u & 0xffff0000u);
  unsigned v = __builtin_bit_cast(unsigned, x - hf);
  v += 0x7fffu + ((v >> 16) & 1u);
  l = (unsigned short)(v >> 16);
}

// Pack two f32 -> u32 holding 2 RNE-rounded bf16.
__device__ inline unsigned rne2(float a, float b) {
  unsigned ua = __builtin_bit_cast(unsigned, a);
  unsigned ub = __builtin_bit_cast(unsigned, b);
  ua += 0x7fffu + ((ua >> 16) & 1u);
  ub += 0x7fffu + ((ub >> 16) & 1u);
  return (ua >> 16) | (ub & 0xffff0000u);
}

struct ProjArgs {
  const float* x;
  const float* W[6];
  const float* bias[6];
};

// ---------------------------------------------------------------------------
// Kernel 1: six 1x1-conv projections, fp32 compute.
// Q/K written transposed ([n][c], c contiguous) split into bf16 hi/lo.
// V written fp32 [c][n] (bf16 RNE happens after the 1/Z fold).
// ---------------------------------------------------------------------------
__global__ __launch_bounds__(256) void proj_kernel(ProjArgs a) {
  __shared__ float Wt[64][68];
  __shared__ float bs[64];
  const int tid = threadIdx.x;
  const int m = blockIdx.z; // 0..5 = qh,kh,vh,ql,kl,vl
  const float* __restrict__ W = a.W[m];
#pragma unroll
  for (int k = 0; k < 16; ++k) {
    int t = k * 256 + tid; // t = o*64 + c
    Wt[t & 63][t >> 6] = W[t];
  }
  if (tid < 64) bs[tid] = a.bias[m][tid];
  __syncthreads();

  const int b = blockIdx.y;
  const int n = (blockIdx.x << 6) + (tid & 63);
  const int og = tid >> 6;
  const float* __restrict__ xp = a.x + ((size_t)b * CD) * NN + n;

  float acc[16];
#pragma unroll
  for (int k = 0; k < 16; ++k) acc[k] = bs[og * 16 + k];

#pragma unroll 4
  for (int c = 0; c < 64; ++c) {
    float xv = xp[(size_t)c * NN];
    float w[16];
    *(float4*)&w[0]  = *(const float4*)&Wt[c][og * 16 + 0];
    *(float4*)&w[4]  = *(const float4*)&Wt[c][og * 16 + 4];
    *(float4*)&w[8]  = *(const float4*)&Wt[c][og * 16 + 8];
    *(float4*)&w[12] = *(const float4*)&Wt[c][og * 16 + 12];
#pragma unroll
    for (int k = 0; k < 16; ++k) acc[k] += w[k] * xv;
  }

  const int br = m / 3, kind = m % 3;
  if (kind == 2) { // V: fp32 [c][n]
    float* dst = &g_Vf[br][b][0][0] + n;
#pragma unroll
    for (int k = 0; k < 16; ++k) dst[(size_t)(og * 16 + k) * NN] = acc[k];
  } else { // Q/K: bf16 hi/lo, transposed [n][c]
    unsigned short hi[16], lo[16];
#pragma unroll
    for (int k = 0; k < 16; ++k) split_bf(acc[k], hi[k], lo[k]);
    unsigned short* dh = (kind == 0) ? &g_Qh[br][b][n][og * 16] : &g_Kh[br][b][n][og * 16];
    unsigned short* dl = (kind == 0) ? &g_Ql[br][b][n][og * 16] : &g_Kl[br][b][n][og * 16];
    *(uint4*)dh       = *(const uint4*)&hi[0];
    *(uint4*)(dh + 8) = *(const uint4*)&hi[8];
    *(uint4*)dl       = *(const uint4*)&lo[0];
    *(uint4*)(dl + 8) = *(const uint4*)&lo[8];
  }
}

// ---------------------------------------------------------------------------
// Kernel 2: pass 1 — Zp[js][i] = sum_{j in js half} exp(S[i,j]).
// grid 1024 (bid&7=image->XCD pin, (bid>>3)&1=j-split, bid>>4=i-block).
// Template: K hi/lo tile (16 KiB) shared by 4 waves in XOR-swizzled LDS,
// reg-staged double buffer (issue at top, commit before the single barrier).
// Q fragments static in registers. setprio(1) around the MFMA cluster.
// ---------------------------------------------------------------------------
__global__ __launch_bounds__(256, 2) void pass1_kernel() {
  __shared__ uint4 sK[2][1024]; // per buf: [0,8K) Kh, [8K,16K) Kl
  __shared__ float zbuf[2][64];

  const int tid = threadIdx.x;
  const int bid = blockIdx.x;
  const int img = bid & 7;
  const int br = img >> 2, b = img & 3;
  const int js = (bid >> 3) & 1;
  const int i0 = (bid >> 4) << 6;

  const int lane = tid & 63, w = tid >> 6;
  const int wi = w >> 1, wj = w & 1;
  const int lm = lane & 15, q = lane >> 4;
  const int swz = (lm & 7) << 4;
  const int srow = lane >> 3;        // staging row-in-chunk 0..7
  const int sbyte = (lane & 7) * 16; // staging byte-in-row

  const char* __restrict__ KhB = (const char*)&g_Kh[br][b][0][0];
  const char* __restrict__ KlB = (const char*)&g_Kl[br][b][0][0];
  const unsigned short* __restrict__ QhB = &g_Qh[br][b][0][0];
  const unsigned short* __restrict__ QlB = &g_Ql[br][b][0][0];

  // Static A-frags (Q): [it][cstep][hi/lo]
  bf16x8 qa[2][2][2];
#pragma unroll
  for (int it = 0; it < 2; ++it)
#pragma unroll
    for (int cs = 0; cs < 2; ++cs) {
      size_t off = (size_t)(i0 + wi * 32 + it * 16 + lm) * 64 + cs * 32 + q * 8;
      qa[it][cs][0] = *(const bf16x8*)(QhB + off);
      qa[it][cs][1] = *(const bf16x8*)(QlB + off);
    }

  // K staging: 16 chunks of 1 KiB (8 rows x 128B); wave w owns chunks w*4..+3.
  auto stage_issue = [&](uint4 (&st)[4], int jb) {
#pragma unroll
    for (int k = 0; k < 4; ++k) {
      int c = w * 4 + k;
      int r = (c & 7) * 8 + srow;
      const char* src = ((c < 8) ? KhB : KlB) + (size_t)(jb + r) * 128 + sbyte;
      st[k] = *(const uint4*)src;
    }
  };
  auto stage_commit = [&](uint4 (&st)[4], int buf) {
    char* base = (char*)&sK[buf][0];
#pragma unroll
    for (int k = 0; k < 4; ++k) {
      int c = w * 4 + k;
      int r = (c & 7) * 8 + srow;
      int reg = (c < 8) ? 0 : 8192;
      *(uint4*)(base + reg + r * 128 + (sbyte ^ (srow << 4))) = st[k];
    }
  };

  { // prologue: tile 0 -> buf 0
    uint4 st[4];
    stage_issue(st, (js << 11)); // jb = (js*32+0)*64
    stage_commit(st, 0);
  }
  __syncthreads();

  float zacc[2][4];
#pragma unroll
  for (int it = 0; it < 2; ++it)
#pragma unroll
    for (int r = 0; r < 4; ++r) zacc[it][r] = 0.f;

  for (int tt = 0; tt < 32; ++tt) {
    const int bsel = tt & 1;
    char* bufc = (char*)&sK[bsel][0];

    uint4 st[4];
    if (tt < 31) stage_issue(st, ((js << 5) + tt + 1) << 6);

    bf16x8 kb[2][2][2]; // [jt][cstep][hi/lo]
#pragma unroll
    for (int jt = 0; jt < 2; ++jt) {
      int row = wj * 32 + jt * 16 + lm;
#pragma unroll
      for (int cs = 0; cs < 2; ++cs) {
        int byo = row * 128 + ((cs * 64 + q * 16) ^ swz);
        kb[jt][cs][0] = *(const bf16x8*)(bufc + byo);
        kb[jt][cs][1] = *(const bf16x8*)(bufc + 8192 + byo);
      }
    }

    const f32x4 zf = {0.f, 0.f, 0.f, 0.f};
    f32x4 s[2][2];
    __builtin_amdgcn_s_setprio(1);
#pragma unroll
    for (int it = 0; it < 2; ++it)
#pragma unroll
      for (int jt = 0; jt < 2; ++jt) {
        f32x4 t = mfma16(qa[it][0][0], kb[jt][0][0], zf);
        t = mfma16(qa[it][1][0], kb[jt][1][0], t);
        t = mfma16(qa[it][0][0], kb[jt][0][1], t);
        t = mfma16(qa[it][1][0], kb[jt][1][1], t);
        t = mfma16(qa[it][0][1], kb[jt][0][0], t);
        t = mfma16(qa[it][1][1], kb[jt][1][0], t);
        s[it][jt] = t;
      }
    __builtin_amdgcn_s_setprio(0);
#pragma unroll
    for (int it = 0; it < 2; ++it)
#pragma unroll
      for (int jt = 0; jt < 2; ++jt) {
        zacc[it][0] += __expf(s[it][jt][0]);
        zacc[it][1] += __expf(s[it][jt][1]);
        zacc[it][2] += __expf(s[it][jt][2]);
        zacc[it][3] += __expf(s[it][jt][3]);
      }

    if (tt < 31) stage_commit(st, bsel ^ 1);
    __syncthreads();
  }

#pragma unroll
  for (int mm = 1; mm < 16; mm <<= 1)
#pragma unroll
    for (int it = 0; it < 2; ++it)
#pragma unroll
      for (int r = 0; r < 4; ++r) zacc[it][r] += __shfl_xor(zacc[it][r], mm, 64);

  if (lm == 0) {
#pragma unroll
    for (int it = 0; it < 2; ++it)
#pragma unroll
      for (int r = 0; r < 4; ++r)
        zbuf[wj][wi * 32 + it * 16 + q * 4 + r] = zacc[it][r];
  }
  __syncthreads();
  if (tid < 64) g_Zp[js][br][b][i0 + tid] = zbuf[0][tid] + zbuf[1][tid];
}

// ---------------------------------------------------------------------------
// Kernel 3: Z = sum of 2 partials; fold g/Z into V; RNE-round to bf16.
// ---------------------------------------------------------------------------
__global__ __launch_bounds__(256) void scalev_kernel(const float* __restrict__ g1,
                                                     const float* __restrict__ g2) {
  int idx = blockIdx.x * 256 + threadIdx.x; // 2*4*64*1024 float4 chunks
  int i4 = idx & 1023;
  int c  = (idx >> 10) & 63;
  int b  = (idx >> 16) & 3;
  int br = idx >> 18;
  float g = br ? g2[0] : g1[0];
  float4 z0 = *(const float4*)&g_Zp[0][br][b][i4 * 4];
  float4 z1 = *(const float4*)&g_Zp[1][br][b][i4 * 4];
  float4 z = {z0.x + z1.x, z0.y + z1.y, z0.z + z1.z, z0.w + z1.w};
  float4 v = *(const float4*)&g_Vf[br][b][c][i4 * 4];
  uint2 uh;
  uh.x = rne2(v.x * g / z.x, v.y * g / z.y);
  uh.y = rne2(v.z * g / z.z, v.w * g / z.w);
  *(uint2*)&g_Vb[br][b][c][i4 * 4] = uh;
}

// ---------------------------------------------------------------------------
// Kernel 4: pass 2 — O[c,j] = sum_i Vb[c,i] * exp(S[i,j])  (g/Z folded in V).
// grid 512 (bid&7 = image -> XCD pin, bid>>3 = 64-col j-block).
// 4 waves 2x2 (wi = i-strip for S / c-strip for PV; wj = j-strip).
// Per 64-i tile: Qh/Ql/Vb (24 KiB) staged into XOR-swizzled LDS shared by
// all waves (reg-staged double buffer, issue-early/commit-late); K-frags
// static in regs; P (single bf16) through double-buffered swizzled LDS.
// ONE __syncthreads per iteration: {all buf reads, stage commit, P writes}
// before it; {P reads + PV} after it.
// ---------------------------------------------------------------------------
__global__ __launch_bounds__(256, 2) void pass2_kernel() {
  __shared__ uint4 sA[2][1536]; // per buf: [0,8K) Qh, [8K,16K) Ql, [16K,24K) Vb
  __shared__ uint4 sP[2][512];  // P tile bf16 [j 64][i 64], swizzled

  const int tid = threadIdx.x;
  const int bid = blockIdx.x;
  const int img = bid & 7;
  const int br = img >> 2, b = img & 3;
  const int j0 = (bid >> 3) << 6;

  const int lane = tid & 63, w = tid >> 6;
  const int wi = w >> 1, wj = w & 1;
  const int lm = lane & 15, q = lane >> 4;
  const int swz = (lm & 7) << 4;
  const int srow = lane >> 3;
  const int sbyte = (lane & 7) * 16;

  const char* __restrict__ QhB = (const char*)&g_Qh[br][b][0][0];
  const char* __restrict__ QlB = (const char*)&g_Ql[br][b][0][0];
  const unsigned short* __restrict__ KhB = &g_Kh[br][b][0][0];
  const unsigned short* __restrict__ KlB = &g_Kl[br][b][0][0];
  const char* __restrict__ VbB = (const char*)&g_Vb[br][b][0][0];

  // Static B-frags (K^T rows = block's j-columns): [jt][cstep][hi/lo]
  bf16x8 kb[2][2][2];
#pragma unroll
  for (int jt = 0; jt < 2; ++jt)
#pragma unroll
    for (int cs = 0; cs < 2; ++cs) {
      size_t off = (size_t)(j0 + wj * 32 + jt * 16 + lm) * 64 + cs * 32 + q * 8;
      kb[jt][cs][0] = *(const bf16x8*)(KhB + off);
      kb[jt][cs][1] = *(const bf16x8*)(KlB + off);
    }

  // Staging: 24 chunks of 1 KiB; wave w owns chunks w*6..+5.
  // c in [0,8): Qh rows c*8.. ; [8,16): Ql; [16,24): Vb (c-channel rows).
  auto stage_issue = [&](uint4 (&st)[6], int i0t) {
#pragma unroll
    for (int k = 0; k < 6; ++k) {
      int c = w * 6 + k;
      int r = (c & 7) * 8 + srow;
      const char* src;
      if (c < 8)       src = QhB + (size_t)(i0t + r) * 128 + sbyte;
      else if (c < 16) src = QlB + (size_t)(i0t + r) * 128 + sbyte;
      else             src = VbB + (size_t)r * (NN * 2) + (size_t)i0t * 2 + sbyte;
      st[k] = *(const uint4*)src;
    }
  };
  auto stage_commit = [&](uint4 (&st)[6], int buf) {
    char* base = (char*)&sA[buf][0];
#pragma unroll
    for (int k = 0; k < 6; ++k) {
      int c = w * 6 + k;
      int r = (c & 7) * 8 + srow;
      int reg = (c < 8) ? 0 : (c < 16) ? 8192 : 16384;
      *(uint4*)(base + reg + r * 128 + (sbyte ^ (srow << 4))) = st[k];
    }
  };

  { // prologue: tile 0 -> buf 0
    uint4 st[6];
    stage_issue(st, 0);
    stage_commit(st, 0);
  }
  __syncthreads();

  f32x4 oacc[2][2];
#pragma unroll
  for (int ct = 0; ct < 2; ++ct)
#pragma unroll
    for (int jt = 0; jt < 2; ++jt) oacc[ct][jt] = (f32x4){0.f, 0.f, 0.f, 0.f};

  for (int tt = 0; tt < 64; ++tt) {
    const int bsel = tt & 1;
    char* bufc = (char*)&sA[bsel][0];
    char* ptc  = (char*)&sP[bsel][0];

    uint4 st[6];
    if (tt < 63) stage_issue(st, (tt + 1) << 6); // lands under S+exp

    // fragment reads from current buffer (all before the barrier)
    bf16x8 qa[2][2][2];
#pragma unroll
    for (int it = 0; it < 2; ++it) {
      int row = wi * 32 + it * 16 + lm;
#pragma unroll
      for (int cs = 0; cs < 2; ++cs) {
        int byo = row * 128 + ((cs * 64 + q * 16) ^ swz);
        qa[it][cs][0] = *(const bf16x8*)(bufc + byo);
        qa[it][cs][1] = *(const bf16x8*)(bufc + 8192 + byo);
      }
    }
    bf16x8 va[2][2];
#pragma unroll
    for (int ct = 0; ct < 2; ++ct) {
      int row = wi * 32 + ct * 16 + lm;
#pragma unroll
      for (int ks = 0; ks < 2; ++ks)
        va[ct][ks] = *(const bf16x8*)(bufc + 16384 + row * 128 + ((ks * 64 + q * 16) ^ swz));
    }

    // ---- S phase: S[i(wi-strip)][j(wj-strip)] hi/lo 3-term ----
    const f32x4 zf = {0.f, 0.f, 0.f, 0.f};
    f32x4 sacc[2][2];
    __builtin_amdgcn_s_setprio(1);
#pragma unroll
    for (int it = 0; it < 2; ++it)
#pragma unroll
      for (int jt = 0; jt < 2; ++jt) {
        f32x4 s = mfma16(qa[it][0][0], kb[jt][0][0], zf);
        s = mfma16(qa[it][1][0], kb[jt][1][0], s);
        s = mfma16(qa[it][0][0], kb[jt][0][1], s);
        s = mfma16(qa[it][1][0], kb[jt][1][1], s);
        s = mfma16(qa[it][0][1], kb[jt][0][0], s);
        s = mfma16(qa[it][1][1], kb[jt][1][0], s);
        sacc[it][jt] = s;
      }
    __builtin_amdgcn_s_setprio(0);

    // ---- exp -> bf16 RNE -> swizzled P tile ----
#pragma unroll
    for (int it = 0; it < 2; ++it)
#pragma unroll
      for (int jt = 0; jt < 2; ++jt) {
        int rowj = wj * 32 + jt * 16 + lm;
        uint2 pk;
        pk.x = rne2(__expf(sacc[it][jt][0]), __expf(sacc[it][jt][1]));
        pk.y = rne2(__expf(sacc[it][jt][2]), __expf(sacc[it][jt][3]));
        *(uint2*)(ptc + rowj * 128 + ((wi * 64 + it * 32 + q * 8) ^ swz)) = pk;
      }

    if (tt < 63) stage_commit(st, bsel ^ 1); // next tile into other buffer
    __syncthreads(); // P visible, stage drained, all buf reads done

    // ---- PV phase: O[c][j] += V[c][i] * P[i][j] over this 64-i tile ----
    bf16x8 pb[2][2]; // [jt][ks]
#pragma unroll
    for (int jt = 0; jt < 2; ++jt) {
      int rowj = wj * 32 + jt * 16 + lm;
#pragma unroll
      for (int ks = 0; ks < 2; ++ks)
        pb[jt][ks] = *(const bf16x8*)(ptc + rowj * 128 + ((ks * 64 + q * 16) ^ swz));
    }
    __builtin_amdgcn_s_setprio(1);
#pragma unroll
    for (int ct = 0; ct < 2; ++ct)
#pragma unroll
      for (int jt = 0; jt < 2; ++jt) {
        f32x4 o = mfma16(va[ct][0], pb[jt][0], oacc[ct][jt]);
        oacc[ct][jt] = mfma16(va[ct][1], pb[jt][1], o);
      }
    __builtin_amdgcn_s_setprio(0);
  }

  float* __restrict__ Ob = &g_O[br][b][0][0];
#pragma unroll
  for (int ct = 0; ct < 2; ++ct)
#pragma unroll
    for (int jt = 0; jt < 2; ++jt)
#pragma unroll
      for (int r = 0; r < 4; ++r)
        Ob[(size_t)(wi * 32 + ct * 16 + q * 4 + r) * NN + j0 + wj * 32 + jt * 16 + lm] =
            oacc[ct][jt][r];
}

// ---------------------------------------------------------------------------
// Kernel 5: final 1x1 conv over concat (g1/g2 already folded into V).
// ---------------------------------------------------------------------------
__global__ __launch_bounds__(256) void final_kernel(const float* __restrict__ Wf,
                                                    const float* __restrict__ bf,
                                                    float* __restrict__ out) {
  __shared__ float Wt[128][68];
  __shared__ float bs[64];
  const int tid = threadIdx.x;
#pragma unroll
  for (int k = 0; k < 32; ++k) {
    int t = k * 256 + tid; // t = o*128 + c'
    Wt[t & 127][t >> 7] = Wf[t];
  }
  if (tid < 64) bs[tid] = bf[tid];
  __syncthreads();

  const int b = blockIdx.y;
  const int n = (blockIdx.x << 6) + (tid & 63);
  const int og = tid >> 6;

  float acc[16];
#pragma unroll
  for (int k = 0; k < 16; ++k) acc[k] = bs[og * 16 + k];

#pragma unroll
  for (int br = 0; br < 2; ++br) {
    const float* __restrict__ Ob = &g_O[br][b][0][0];
#pragma unroll 4
    for (int c = 0; c < 64; ++c) {
      float xv = Ob[(size_t)c * NN + n];
      float wv[16];
      *(float4*)&wv[0]  = *(const float4*)&Wt[br * 64 + c][og * 16 + 0];
      *(float4*)&wv[4]  = *(const float4*)&Wt[br * 64 + c][og * 16 + 4];
      *(float4*)&wv[8]  = *(const float4*)&Wt[br * 64 + c][og * 16 + 8];
      *(float4*)&wv[12] = *(const float4*)&Wt[br * 64 + c][og * 16 + 12];
#pragma unroll
      for (int k = 0; k < 16; ++k) acc[k] += wv[k] * xv;
    }
  }

  float* op = out + ((size_t)b * CD) * NN + n;
#pragma unroll
  for (int k = 0; k < 16; ++k) op[(size_t)(og * 16 + k) * NN] = acc[k];
}

// ---------------------------------------------------------------------------
extern "C" void kernel_launch(void* const* d_in, const int* in_sizes, int n_in,
                              void* d_out, int out_size, void* d_ws, size_t ws_size,
                              hipStream_t stream) {
  (void)in_sizes; (void)n_in; (void)d_ws; (void)ws_size; (void)out_size;

  ProjArgs pa;
  pa.x = (const float*)d_in[0];
  for (int m = 0; m < 6; ++m) {
    pa.W[m]    = (const float*)d_in[1 + 2 * m];
    pa.bias[m] = (const float*)d_in[2 + 2 * m];
  }
  const float* g1 = (const float*)d_in[13];
  const float* g2 = (const float*)d_in[14];
  const float* Wf = (const float*)d_in[15];
  const float* bf = (const float*)d_in[16];
  float* out = (float*)d_out;

  proj_kernel<<<dim3(64, 4, 6), 256, 0, stream>>>(pa);
  pass1_kernel<<<dim3(1024), 256, 0, stream>>>();
  scalev_kernel<<<dim3(2048), 256, 0, stream>>>(g1, g2);
  pass2_kernel<<<dim3(512), 256, 0, stream>>>();
  final_kernel<<<dim3(64, 4), 256, 0, stream>>>(Wf, bf, out);
}